// Round 2
// baseline (219.924 us; speedup 1.0000x reference)
//
#include <hip/hip_runtime.h>

#define H_LEN 16384
#define ATT_DIM 512
#define DUNITS 1024
#define EPROJS 512
#define NCH 10
#define KFILT 201
#define PAD 100
#define N_PREV 128
#define NBLK 512      // k_score blocks, 32 h each
#define NCOVP 16      // cov partials (n-groups of 8)

// ---------------------------------------------------------------------------
// K1: fused prep. 385 blocks x 256.
//  b in [0,256)   : float4 copy + partial coverage (att_prev read ONCE).
//                   h-chunk = b>>4 (16 chunks x 1024 floats), n-group = b&15 (8 n).
//  b in [256,384) : dz[a] = mlp_dec_w[a,:] . dec_z (one wave per a)
//  b == 384       : zero the arrival counter (workspace is poisoned per iter)
__global__ __launch_bounds__(256) void k_prep(const float* __restrict__ att_prev,
                                              const float* __restrict__ mlp_dec_w,
                                              const float* __restrict__ dec_z,
                                              float* __restrict__ out_prev,
                                              float* __restrict__ cov16,
                                              float* __restrict__ dz,
                                              int* __restrict__ cnt) {
    int b = blockIdx.x, tid = threadIdx.x;
    if (b < 256) {
        const float4* ap4 = (const float4*)att_prev;
        float4* op4 = (float4*)out_prev;
        float4* cv4 = (float4*)cov16;
        int hb = b >> 4, q = b & 15;
        int idx0 = hb * 256 + tid;               // float4 index in a row: [0, 4096)
        float4 s = {0.f, 0.f, 0.f, 0.f};
        #pragma unroll
        for (int n = q * 8; n < q * 8 + 8; ++n) {
            float4 v = ap4[n * (H_LEN / 4) + idx0];
            s.x += v.x; s.y += v.y; s.z += v.z; s.w += v.w;
            op4[n * (H_LEN / 4) + idx0] = v;
        }
        cv4[q * (H_LEN / 4) + idx0] = s;
    } else if (b < 384) {
        int lane = tid & 63;
        int a = (b - 256) * 4 + (tid >> 6);
        const float* row = mlp_dec_w + a * DUNITS;
        float s = 0.f;
        #pragma unroll
        for (int t = 0; t < DUNITS / 64; ++t) s += row[lane + 64 * t] * dec_z[lane + 64 * t];
        #pragma unroll
        for (int off = 32; off > 0; off >>= 1) s += __shfl_xor(s, off, 64);
        if (lane == 0) dz[a] = s;
    } else {
        if (tid == 0) *cnt = 0;
    }
}

// ---------------------------------------------------------------------------
// K2: conv + score + per-block softmax partials + unnormalized context partial,
// then LAST-ARRIVING block finalizes (merge partials, out_w, out_c).
// Deadlock-free: no block ever waits; exactly one block observes old==NBLK-1,
// and at that point every block's partials are globally visible (release =
// threadfence+syncthreads before the atomic; acquire = threadfence after).
__global__ __launch_bounds__(256, 2) void k_score(const float* __restrict__ cov16,
                                                  const float* __restrict__ cw,
                                                  const float* __restrict__ pre,
                                                  const float* __restrict__ mask,
                                                  const float* __restrict__ dz,
                                                  const float* __restrict__ watt,
                                                  const float* __restrict__ gv,
                                                  const float* __restrict__ gb,
                                                  const float* __restrict__ enc,
                                                  float* __restrict__ vbuf,
                                                  float* __restrict__ pm,
                                                  float* __restrict__ ps,
                                                  float* __restrict__ pcb,
                                                  float* __restrict__ out_w,
                                                  float* __restrict__ out_c,
                                                  int* __restrict__ cnt) {
    __shared__ float cov_s[32 + 2 * PAD];   // 232
    __shared__ float mask_s[32];
    __shared__ float pc[8][NCH][32];        // partial conv per tap-eighth (race-free)
    __shared__ float cf[NCH][32];           // final conv
    __shared__ float vt[32];                // scores
    __shared__ float wt[32];                // exp(v - M_b)
    __shared__ float scale_s[NBLK];         // finalize: per-block rescale
    __shared__ float4 ctmp[128];            // finalize: half-combine
    __shared__ float redA[4], redB[4];
    __shared__ int isLast;

    int tid = threadIdx.x, b = blockIdx.x;
    int h0 = b * 32;
    int lane = tid & 63, wv = tid >> 6;
    int a0 = lane * 4;

    // stage LDS: cov window (sum the 16 n-partials) + mask
    for (int i = tid; i < 32 + 2 * PAD; i += 256) {
        int g = h0 - PAD + i;
        float s = 0.f;
        if (g >= 0 && g < H_LEN) {
            #pragma unroll
            for (int q = 0; q < NCOVP; ++q) s += cov16[q * H_LEN + g];
        }
        cov_s[i] = s;
    }
    if (tid < 32) mask_s[tid] = mask[h0 + tid];

    // preload ALL pre fragments for this wave's 8 h (64 VGPRs in flight);
    // conv compute below covers the latency.
    const float4* pre4 = (const float4*)pre;
    int hbase = h0 + wv * 8;
    float4 P[16];
    #pragma unroll
    for (int j = 0; j < 8; ++j) {
        P[2 * j]     = pre4[(hbase + j) * 128 + lane];
        P[2 * j + 1] = pre4[(hbase + j) * 128 + 64 + lane];
    }

    // per-lane weights in registers
    float Wr[8][NCH], dzr[8], gvr[8];
    #pragma unroll
    for (int i = 0; i < 8; ++i) {
        int a = (i < 4) ? (a0 + i) : (a0 + 256 + (i - 4));
        dzr[i] = dz[a];
        gvr[i] = gv[a];
        #pragma unroll
        for (int c = 0; c < NCH; ++c) Wr[i][c] = watt[a * NCH + c];
    }
    float bias = gb[0];
    __syncthreads();

    // conv: 8 tap-groups (q = tid>>5), h = tid&31; k-index wave-uniform -> s_load
    {
        int h = tid & 31, q = tid >> 5;            // q in [0,8)
        int k0 = (q * KFILT) / 8, k1 = ((q + 1) * KFILT) / 8;
        float acc[NCH];
        #pragma unroll
        for (int c = 0; c < NCH; ++c) acc[c] = 0.f;
        for (int k = k0; k < k1; ++k) {
            float s = cov_s[h + k];
            #pragma unroll
            for (int c = 0; c < NCH; ++c) acc[c] += s * cw[c * KFILT + k];
        }
        #pragma unroll
        for (int c = 0; c < NCH; ++c) pc[q][c][h] = acc[c];   // distinct slot per q
    }
    __syncthreads();
    for (int i = tid; i < NCH * 32; i += 256) {
        int c = i >> 5, h = i & 31;
        float s = 0.f;
        #pragma unroll
        for (int q = 0; q < 8; ++q) s += pc[q][c][h];
        cf[c][h] = s;
    }
    __syncthreads();

    // score: wave wv handles h in [8*wv, 8*wv+8).
    // Compute all 8 partial sums first, then ONE 6-step butterfly with
    // 8-wide ILP (identical arithmetic to 8 serial chains, ~6x less
    // exposed shuffle latency).
    float ea[8];
    #pragma unroll
    for (int j = 0; j < 8; ++j) {
        int hh = wv * 8 + j;
        float ch[NCH];
        #pragma unroll
        for (int c = 0; c < NCH; ++c) ch[c] = cf[c][hh];   // broadcast
        float4 c0 = P[2 * j], c1 = P[2 * j + 1];
        float pv[8] = {c0.x, c0.y, c0.z, c0.w, c1.x, c1.y, c1.z, c1.w};
        float eacc = 0.f;
        #pragma unroll
        for (int i = 0; i < 8; ++i) {
            float x = pv[i] + dzr[i];
            #pragma unroll
            for (int c = 0; c < NCH; ++c) x += ch[c] * Wr[i][c];
            x = fminf(fmaxf(x, -15.f), 15.f);
            float z = __expf(2.f * x);                      // tanh via exp + rcp
            float t = (z - 1.f) * __builtin_amdgcn_rcpf(z + 1.f);
            eacc += t * gvr[i];
        }
        ea[j] = eacc;
    }
    #pragma unroll
    for (int off = 32; off > 0; off >>= 1) {
        #pragma unroll
        for (int j = 0; j < 8; ++j) ea[j] += __shfl_xor(ea[j], off, 64);
    }
    if (lane == 0) {
        #pragma unroll
        for (int j = 0; j < 8; ++j) {
            int hh = wv * 8 + j;
            float v = 2.f * (ea[j] + bias + mask_s[hh]);
            vt[hh] = v;
            vbuf[h0 + hh] = v;
        }
    }
    __syncthreads();

    // wave 0: block softmax partials M_b, s_b; stage wt[h] = exp(v - M_b)
    if (wv == 0) {
        float v = (lane < 32) ? vt[lane] : -1e30f;
        float m = v;
        #pragma unroll
        for (int off = 32; off > 0; off >>= 1) m = fmaxf(m, __shfl_xor(m, off, 64));
        float ev = (lane < 32) ? __expf(v - m) : 0.f;
        if (lane < 32) wt[lane] = ev;
        float s = ev;
        #pragma unroll
        for (int off = 32; off > 0; off >>= 1) s += __shfl_xor(s, off, 64);
        if (lane == 0) { pm[b] = m; ps[b] = s; }
    }
    __syncthreads();

    // unnormalized context partial: thread t owns a = {2t, 2t+1}.
    const float2* enc2 = (const float2*)enc;
    float2 acc0 = {0.f, 0.f}, acc1 = {0.f, 0.f};
    #pragma unroll
    for (int h = 0; h < 32; h += 2) {
        float w0 = wt[h], w1 = wt[h + 1];
        float2 e0 = enc2[(h0 + h) * 256 + tid];
        float2 e1 = enc2[(h0 + h + 1) * 256 + tid];
        acc0.x += w0 * e0.x; acc0.y += w0 * e0.y;
        acc1.x += w1 * e1.x; acc1.y += w1 * e1.y;
    }
    float2 accv = {acc0.x + acc1.x, acc0.y + acc1.y};
    ((float2*)pcb)[b * 256 + tid] = accv;

    // ---- completion protocol (release) ------------------------------------
    __threadfence();            // device scope: partials visible cross-XCD
    __syncthreads();            // all threads' fences done before the atomic
    if (tid == 0) isLast = (atomicAdd(cnt, 1) == NBLK - 1);
    __syncthreads();
    if (!isLast) return;
    __threadfence();            // acquire side

    // ---- finalize (single block; all 512 partials globally visible) -------
    float m0 = pm[tid], m1 = pm[tid + 256];
    float s0 = ps[tid], s1 = ps[tid + 256];
    float m = fmaxf(m0, m1);
    #pragma unroll
    for (int off = 32; off > 0; off >>= 1) m = fmaxf(m, __shfl_xor(m, off, 64));
    if (lane == 0) redA[wv] = m;
    __syncthreads();
    float M = fmaxf(fmaxf(redA[0], redA[1]), fmaxf(redA[2], redA[3]));
    float e0 = __expf(m0 - M), e1 = __expf(m1 - M);
    float s = s0 * e0 + s1 * e1;
    #pragma unroll
    for (int off = 32; off > 0; off >>= 1) s += __shfl_xor(s, off, 64);
    if (lane == 0) redB[wv] = s;
    __syncthreads();
    float S = redB[0] + redB[1] + redB[2] + redB[3];
    float rinv = 1.f / S;
    scale_s[tid] = e0 * rinv;
    scale_s[tid + 256] = e1 * rinv;
    __syncthreads();

    // out_w: 16384 floats, float4-vectorized
    {
        const float4* vb4 = (const float4*)vbuf;
        float4* ow4 = (float4*)out_w;
        for (int i = tid; i < H_LEN / 4; i += 256) {
            float4 v = vb4[i];
            float4 o = { __expf(v.x - M) * rinv, __expf(v.y - M) * rinv,
                         __expf(v.z - M) * rinv, __expf(v.w - M) * rinv };
            ow4[i] = o;
        }
    }

    // out_c: thread t owns f4-col (t&127), row-half (t>>7); 1 MB from L2/L3
    {
        const float4* pcb4 = (const float4*)pcb;
        int c = tid & 127, half = tid >> 7;
        float4 acc = {0.f, 0.f, 0.f, 0.f};
        int r0 = half * 256;
        #pragma unroll 4
        for (int r = r0; r < r0 + 256; ++r) {
            float sc = scale_s[r];
            float4 p = pcb4[r * 128 + c];
            acc.x += sc * p.x; acc.y += sc * p.y;
            acc.z += sc * p.z; acc.w += sc * p.w;
        }
        if (half) ctmp[c] = acc;
        __syncthreads();
        if (!half) {
            float4 o = ctmp[c];
            acc.x += o.x; acc.y += o.y; acc.z += o.z; acc.w += o.w;
            ((float4*)out_c)[c] = acc;
        }
    }
}

// ---------------------------------------------------------------------------
extern "C" void kernel_launch(void* const* d_in, const int* in_sizes, int n_in,
                              void* d_out, int out_size, void* d_ws, size_t ws_size,
                              hipStream_t stream) {
    const float* dec_z      = (const float*)d_in[0];
    const float* att_prev   = (const float*)d_in[1];
    const float* pre        = (const float*)d_in[2];
    const float* enc_h      = (const float*)d_in[3];
    const float* mask       = (const float*)d_in[4];
    const float* loc_conv_w = (const float*)d_in[5];
    const float* mlp_att_w  = (const float*)d_in[6];
    const float* mlp_dec_w  = (const float*)d_in[7];
    const float* gvec_w     = (const float*)d_in[8];
    const float* gvec_b     = (const float*)d_in[9];

    float* out_c    = (float*)d_out;                  // [512]
    float* out_prev = out_c + EPROJS;                 // [128*16384]
    float* out_w    = out_prev + N_PREV * H_LEN;      // [16384]

    float* ws    = (float*)d_ws;
    float* cov16 = ws;                                // 16*16384
    float* dz    = cov16 + NCOVP * H_LEN;             // 512
    float* vb    = dz + ATT_DIM;                      // 16384
    float* pm    = vb + H_LEN;                        // 512
    float* ps    = pm + NBLK;                         // 512
    float* pcb   = ps + NBLK;                         // 512*512
    int*   cnt   = (int*)(pcb + NBLK * EPROJS);       // 1

    k_prep<<<385, 256, 0, stream>>>(att_prev, mlp_dec_w, dec_z, out_prev, cov16, dz, cnt);
    k_score<<<NBLK, 256, 0, stream>>>(cov16, loc_conv_w, pre, mask, dz, mlp_att_w,
                                      gvec_w, gvec_b, enc_h, vb, pm, ps, pcb,
                                      out_w, out_c, cnt);
}

// Round 4
// 147.059 us; speedup vs baseline: 1.4955x; 1.4955x over previous
//
#include <hip/hip_runtime.h>

#define H_LEN 16384
#define ATT_DIM 512
#define DUNITS 1024
#define EPROJS 512
#define NCH 10
#define KFILT 201
#define PAD 100
#define N_PREV 128
#define HB 16          // h per k_score block
#define NBLK 1024      // k_score blocks
#define NB_FIN 256     // k_final blocks
#define NCOVP 16       // cov partials (n-groups of 8)

// ---------------------------------------------------------------------------
// K1: fused prep. 385 blocks x 256.
//  b in [0,256)   : float4 copy + partial coverage (att_prev read ONCE).
//  b in [256,384) : dz[a] = mlp_dec_w[a,:] . dec_z (one wave per a)
//  b == 384       : zero out_c (atomic target of k_final)
__global__ __launch_bounds__(256) void k_prep(const float* __restrict__ att_prev,
                                              const float* __restrict__ mlp_dec_w,
                                              const float* __restrict__ dec_z,
                                              float* __restrict__ out_prev,
                                              float* __restrict__ cov16,
                                              float* __restrict__ dz,
                                              float* __restrict__ out_c) {
    int b = blockIdx.x, tid = threadIdx.x;
    if (b < 256) {
        const float4* ap4 = (const float4*)att_prev;
        float4* op4 = (float4*)out_prev;
        float4* cv4 = (float4*)cov16;
        int hb = b >> 4, q = b & 15;
        int idx0 = hb * 256 + tid;               // float4 index in a row: [0, 4096)
        float4 s = {0.f, 0.f, 0.f, 0.f};
        #pragma unroll
        for (int n = q * 8; n < q * 8 + 8; ++n) {
            float4 v = ap4[n * (H_LEN / 4) + idx0];
            s.x += v.x; s.y += v.y; s.z += v.z; s.w += v.w;
            op4[n * (H_LEN / 4) + idx0] = v;
        }
        cv4[q * (H_LEN / 4) + idx0] = s;
    } else if (b < 384) {
        int lane = tid & 63;
        int a = (b - 256) * 4 + (tid >> 6);
        const float* row = mlp_dec_w + a * DUNITS;
        float s = 0.f;
        #pragma unroll
        for (int t = 0; t < DUNITS / 64; ++t) s += row[lane + 64 * t] * dec_z[lane + 64 * t];
        #pragma unroll
        for (int off = 32; off > 0; off >>= 1) s += __shfl_xor(s, off, 64);
        if (lane == 0) dz[a] = s;
    } else {
        out_c[tid] = 0.f;
        out_c[tid + 256] = 0.f;
    }
}

// ---------------------------------------------------------------------------
// K2: conv + score + per-block softmax partials + unnormalized context partial.
// 1024 blocks x 16 h each, 3 blocks/CU resident (latency hiding), ~12 KB LDS.
__global__ __launch_bounds__(256, 3) void k_score(const float* __restrict__ cov16,
                                                  const float* __restrict__ cw,
                                                  const float* __restrict__ pre,
                                                  const float* __restrict__ mask,
                                                  const float* __restrict__ dz,
                                                  const float* __restrict__ watt,
                                                  const float* __restrict__ gv,
                                                  const float* __restrict__ gb,
                                                  const float* __restrict__ enc,
                                                  float* __restrict__ vbuf,
                                                  float* __restrict__ pm,
                                                  float* __restrict__ ps,
                                                  float* __restrict__ pcb) {
    __shared__ float cov_s[HB + 2 * PAD];   // 216
    __shared__ float mask_s[HB];
    __shared__ float pc[16][NCH][HB];       // partial conv per tap-16th (10 KB)
    __shared__ float cf[NCH][HB];           // final conv
    __shared__ float vt[HB];                // scores
    __shared__ float wt[HB];                // exp(v - M_b)

    int tid = threadIdx.x, b = blockIdx.x;
    int h0 = b * HB;
    int lane = tid & 63, wv = tid >> 6;
    int a0 = lane * 4;

    // stage LDS: cov window (sum the 16 n-partials) + mask
    for (int i = tid; i < HB + 2 * PAD; i += 256) {
        int g = h0 - PAD + i;
        float s = 0.f;
        if (g >= 0 && g < H_LEN) {
            #pragma unroll
            for (int q = 0; q < NCOVP; ++q) s += cov16[q * H_LEN + g];
        }
        cov_s[i] = s;
    }
    if (tid < HB) mask_s[tid] = mask[h0 + tid];

    // preload pre fragments for this wave's 4 h; conv covers the latency
    const float4* pre4 = (const float4*)pre;
    int hbase = h0 + wv * 4;
    float4 P[8];
    #pragma unroll
    for (int j = 0; j < 4; ++j) {
        P[2 * j]     = pre4[(hbase + j) * 128 + lane];
        P[2 * j + 1] = pre4[(hbase + j) * 128 + 64 + lane];
    }

    // per-lane weights in registers (lane covers a = a0..a0+3 and a0+256..+259)
    float Wr[8][NCH], dzr[8], gvr[8];
    #pragma unroll
    for (int i = 0; i < 8; ++i) {
        int a = (i < 4) ? (a0 + i) : (a0 + 256 + (i - 4));
        dzr[i] = dz[a];
        gvr[i] = gv[a];
        #pragma unroll
        for (int c = 0; c < NCH; ++c) Wr[i][c] = watt[a * NCH + c];
    }
    float bias = gb[0];
    __syncthreads();

    // conv: 16 tap-groups (q = tid>>4, ~13 taps each), h = tid&15
    {
        int h = tid & 15, q = tid >> 4;            // q in [0,16)
        int k0 = (q * KFILT) / 16, k1 = ((q + 1) * KFILT) / 16;
        float acc[NCH];
        #pragma unroll
        for (int c = 0; c < NCH; ++c) acc[c] = 0.f;
        for (int k = k0; k < k1; ++k) {
            float s = cov_s[h + k];
            #pragma unroll
            for (int c = 0; c < NCH; ++c) acc[c] += s * cw[c * KFILT + k];
        }
        #pragma unroll
        for (int c = 0; c < NCH; ++c) pc[q][c][h] = acc[c];   // distinct slot per q
    }
    __syncthreads();
    for (int i = tid; i < NCH * HB; i += 256) {     // 160 entries
        int c = i >> 4, h = i & 15;
        float s = 0.f;
        #pragma unroll
        for (int q = 0; q < 16; ++q) s += pc[q][c][h];
        cf[c][h] = s;
    }
    __syncthreads();

    // score: wave wv handles h in [4*wv, 4*wv+4); compute 4 partial sums,
    // then ONE 6-step butterfly with 4-wide ILP
    float ea[4];
    #pragma unroll
    for (int j = 0; j < 4; ++j) {
        int hh = wv * 4 + j;
        float ch[NCH];
        #pragma unroll
        for (int c = 0; c < NCH; ++c) ch[c] = cf[c][hh];   // broadcast
        float4 c0 = P[2 * j], c1 = P[2 * j + 1];
        float pv[8] = {c0.x, c0.y, c0.z, c0.w, c1.x, c1.y, c1.z, c1.w};
        float eacc = 0.f;
        #pragma unroll
        for (int i = 0; i < 8; ++i) {
            float x = pv[i] + dzr[i];
            #pragma unroll
            for (int c = 0; c < NCH; ++c) x += ch[c] * Wr[i][c];
            x = fminf(fmaxf(x, -15.f), 15.f);
            float z = __expf(2.f * x);                      // tanh via exp + rcp
            float t = (z - 1.f) * __builtin_amdgcn_rcpf(z + 1.f);
            eacc += t * gvr[i];
        }
        ea[j] = eacc;
    }
    #pragma unroll
    for (int off = 32; off > 0; off >>= 1) {
        #pragma unroll
        for (int j = 0; j < 4; ++j) ea[j] += __shfl_xor(ea[j], off, 64);
    }
    if (lane == 0) {
        #pragma unroll
        for (int j = 0; j < 4; ++j) {
            int hh = wv * 4 + j;
            float v = 2.f * (ea[j] + bias + mask_s[hh]);
            vt[hh] = v;
            vbuf[h0 + hh] = v;
        }
    }
    __syncthreads();

    // wave 0: block softmax partials M_b, s_b; stage wt[h] = exp(v - M_b)
    if (wv == 0) {
        float v = (lane < HB) ? vt[lane] : -1e30f;
        float m = v;
        #pragma unroll
        for (int off = 32; off > 0; off >>= 1) m = fmaxf(m, __shfl_xor(m, off, 64));
        float ev = (lane < HB) ? __expf(v - m) : 0.f;
        if (lane < HB) wt[lane] = ev;
        float s = ev;
        #pragma unroll
        for (int off = 32; off > 0; off >>= 1) s += __shfl_xor(s, off, 64);
        if (lane == 0) { pm[b] = m; ps[b] = s; }
    }
    __syncthreads();

    // unnormalized context partial: thread t owns enc cols {2t, 2t+1}
    const float2* enc2 = (const float2*)enc;
    float2 acc0 = {0.f, 0.f}, acc1 = {0.f, 0.f};
    #pragma unroll
    for (int h = 0; h < HB; h += 2) {
        float w0 = wt[h], w1 = wt[h + 1];
        float2 e0 = enc2[(h0 + h) * 256 + tid];
        float2 e1 = enc2[(h0 + h + 1) * 256 + tid];
        acc0.x += w0 * e0.x; acc0.y += w0 * e0.y;
        acc1.x += w1 * e1.x; acc1.y += w1 * e1.y;
    }
    float2 accv = {acc0.x + acc1.x, acc0.y + acc1.y};
    ((float2*)pcb)[b * 256 + tid] = accv;
}

// ---------------------------------------------------------------------------
// K3: finalize. 256 blocks x 256 thr. Redundant merge of 1024 (m,s) partials
// (8 KB, L2-hot); block b writes w for 64 h; reduces pcb rows 4b..4b+3 into
// out_c with rescale, via atomics (256 adds/address).
__global__ __launch_bounds__(256) void k_final(const float* __restrict__ vbuf,
                                               const float* __restrict__ pm,
                                               const float* __restrict__ ps,
                                               const float* __restrict__ pcb,
                                               float* __restrict__ out_w,
                                               float* __restrict__ out_c) {
    __shared__ float redA[4], redB[4];
    int tid = threadIdx.x, b = blockIdx.x;
    int lane = tid & 63, wv = tid >> 6;

    float mr[4], sr[4];
    #pragma unroll
    for (int k = 0; k < 4; ++k) { mr[k] = pm[tid + 256 * k]; sr[k] = ps[tid + 256 * k]; }
    float m = fmaxf(fmaxf(mr[0], mr[1]), fmaxf(mr[2], mr[3]));
    #pragma unroll
    for (int off = 32; off > 0; off >>= 1) m = fmaxf(m, __shfl_xor(m, off, 64));
    if (lane == 0) redA[wv] = m;
    __syncthreads();
    float M = fmaxf(fmaxf(redA[0], redA[1]), fmaxf(redA[2], redA[3]));
    float s = 0.f;
    #pragma unroll
    for (int k = 0; k < 4; ++k) s += sr[k] * __expf(mr[k] - M);
    #pragma unroll
    for (int off = 32; off > 0; off >>= 1) s += __shfl_xor(s, off, 64);
    if (lane == 0) redB[wv] = s;
    __syncthreads();
    float S = redB[0] + redB[1] + redB[2] + redB[3];
    float rinv = 1.f / S;

    // w output: 64 h per block
    if (tid < 64) {
        int h = b * 64 + tid;
        out_w[h] = __expf(vbuf[h] - M) * rinv;
    }

    // context reduction: rows 4b..4b+3 of pcb
    float v0 = 0.f, v1 = 0.f;
    #pragma unroll
    for (int r = 0; r < 4; ++r) {
        int row = 4 * b + r;
        float sc = __expf(pm[row] - M) * rinv;
        v0 += pcb[row * EPROJS + tid] * sc;
        v1 += pcb[row * EPROJS + tid + 256] * sc;
    }
    atomicAdd(&out_c[tid], v0);
    atomicAdd(&out_c[tid + 256], v1);
}

// ---------------------------------------------------------------------------
extern "C" void kernel_launch(void* const* d_in, const int* in_sizes, int n_in,
                              void* d_out, int out_size, void* d_ws, size_t ws_size,
                              hipStream_t stream) {
    const float* dec_z      = (const float*)d_in[0];
    const float* att_prev   = (const float*)d_in[1];
    const float* pre        = (const float*)d_in[2];
    const float* enc_h      = (const float*)d_in[3];
    const float* mask       = (const float*)d_in[4];
    const float* loc_conv_w = (const float*)d_in[5];
    const float* mlp_att_w  = (const float*)d_in[6];
    const float* mlp_dec_w  = (const float*)d_in[7];
    const float* gvec_w     = (const float*)d_in[8];
    const float* gvec_b     = (const float*)d_in[9];

    float* out_c    = (float*)d_out;                  // [512]
    float* out_prev = out_c + EPROJS;                 // [128*16384]
    float* out_w    = out_prev + N_PREV * H_LEN;      // [16384]

    float* ws    = (float*)d_ws;
    float* cov16 = ws;                                // 16*16384
    float* dz    = cov16 + NCOVP * H_LEN;             // 512
    float* vb    = dz + ATT_DIM;                      // 16384
    float* pm    = vb + H_LEN;                        // 1024
    float* ps    = pm + NBLK;                         // 1024
    float* pcb   = ps + NBLK;                         // 1024*512

    k_prep<<<385, 256, 0, stream>>>(att_prev, mlp_dec_w, dec_z, out_prev, cov16, dz, out_c);
    k_score<<<NBLK, 256, 0, stream>>>(cov16, loc_conv_w, pre, mask, dz, mlp_att_w,
                                      gvec_w, gvec_b, enc_h, vb, pm, ps, pcb);
    k_final<<<NB_FIN, 256, 0, stream>>>(vb, pm, ps, pcb, out_w, out_c);
}

// Round 5
// 139.197 us; speedup vs baseline: 1.5799x; 1.0565x over previous
//
#include <hip/hip_runtime.h>

#define H_LEN 16384
#define ATT_DIM 512
#define DUNITS 1024
#define EPROJS 512
#define NCH 10
#define KFILT 201
#define PAD 100
#define N_PREV 128
#define HB 32          // h per k_score block
#define NB_SCORE 512   // k_score blocks
#define NB_FIN 256     // k_final blocks
#define NCOVP 16       // cov partials (n-groups of 8)

// ---------------------------------------------------------------------------
// K1: fused prep. 385 blocks x 256.
//  b in [0,256)   : float4 copy + partial coverage (att_prev read ONCE).
//  b in [256,384) : dz[a] = mlp_dec_w[a,:] . dec_z (one wave per a)
//  b == 384       : zero out_c + transpose watt[512][10] -> wattT[10][512]
__global__ __launch_bounds__(256) void k_prep(const float* __restrict__ att_prev,
                                              const float* __restrict__ mlp_dec_w,
                                              const float* __restrict__ dec_z,
                                              const float* __restrict__ watt,
                                              float* __restrict__ out_prev,
                                              float* __restrict__ cov16,
                                              float* __restrict__ dz,
                                              float* __restrict__ wattT,
                                              float* __restrict__ out_c) {
    int b = blockIdx.x, tid = threadIdx.x;
    if (b < 256) {
        const float4* ap4 = (const float4*)att_prev;
        float4* op4 = (float4*)out_prev;
        float4* cv4 = (float4*)cov16;
        int hb = b >> 4, q = b & 15;
        int idx0 = hb * 256 + tid;               // float4 index in a row: [0, 4096)
        float4 s = {0.f, 0.f, 0.f, 0.f};
        #pragma unroll
        for (int n = q * 8; n < q * 8 + 8; ++n) {
            float4 v = ap4[n * (H_LEN / 4) + idx0];
            s.x += v.x; s.y += v.y; s.z += v.z; s.w += v.w;
            op4[n * (H_LEN / 4) + idx0] = v;
        }
        cv4[q * (H_LEN / 4) + idx0] = s;
    } else if (b < 384) {
        int lane = tid & 63;
        int a = (b - 256) * 4 + (tid >> 6);
        const float* row = mlp_dec_w + a * DUNITS;
        float s = 0.f;
        #pragma unroll
        for (int t = 0; t < DUNITS / 64; ++t) s += row[lane + 64 * t] * dec_z[lane + 64 * t];
        #pragma unroll
        for (int off = 32; off > 0; off >>= 1) s += __shfl_xor(s, off, 64);
        if (lane == 0) dz[a] = s;
    } else {
        out_c[tid] = 0.f;
        out_c[tid + 256] = 0.f;
        int a = tid * 2;                          // transpose 20 KB, once
        #pragma unroll
        for (int c = 0; c < NCH; ++c) {
            wattT[c * ATT_DIM + a]     = watt[a * NCH + c];
            wattT[c * ATT_DIM + a + 1] = watt[(a + 1) * NCH + c];
        }
    }
}

// ---------------------------------------------------------------------------
// K2: conv + score + per-block softmax partials + unnormalized context partial.
// 512 blocks x 32 h. NEW work mapping for the score phase: wave wv owns
// a in [128*wv, 128*wv+128), lane owns 2 consecutive a -> per-thread weights
// are W[2][10] (20 VGPR, no spills) and ALL global loads are coalesced.
__global__ __launch_bounds__(256, 2) void k_score(const float* __restrict__ cov16,
                                                  const float* __restrict__ cw,
                                                  const float* __restrict__ pre,
                                                  const float* __restrict__ mask,
                                                  const float* __restrict__ dz,
                                                  const float* __restrict__ wattT,
                                                  const float* __restrict__ gv,
                                                  const float* __restrict__ gb,
                                                  const float* __restrict__ enc,
                                                  float* __restrict__ vbuf,
                                                  float* __restrict__ pm,
                                                  float* __restrict__ ps,
                                                  float* __restrict__ pcb) {
    __shared__ float cov_s[HB + 2 * PAD];   // 232
    __shared__ float mask_s[HB];
    __shared__ float pc[8][NCH][HB];        // partial conv per tap-eighth (10 KB)
    __shared__ float cfT[HB * 12];          // conv result, [h][c] padded to 12
    __shared__ float ew[4][HB];             // per-wave e partials
    __shared__ float wt[HB];                // exp(v - M_b)

    int tid = threadIdx.x, b = blockIdx.x;
    int h0 = b * HB;
    int lane = tid & 63, wv = tid >> 6;

    // stage LDS: cov window (sum the 16 n-partials) + mask
    for (int i = tid; i < HB + 2 * PAD; i += 256) {
        int g = h0 - PAD + i;
        float s = 0.f;
        if (g >= 0 && g < H_LEN) {
            #pragma unroll
            for (int q = 0; q < NCOVP; ++q) s += cov16[q * H_LEN + g];
        }
        cov_s[i] = s;
    }
    if (tid < HB) mask_s[tid] = mask[h0 + tid];

    // per-thread weights, ALL coalesced float2 (a = 128*wv + 2*lane)
    int a = (wv << 7) + (lane << 1);
    float2 dz2 = *(const float2*)(dz + a);
    float2 gv2 = *(const float2*)(gv + a);
    float W0[NCH], W1[NCH];
    #pragma unroll
    for (int c = 0; c < NCH; ++c) {
        float2 w = *(const float2*)(wattT + c * ATT_DIM + a);
        W0[c] = w.x; W1[c] = w.y;
    }
    float bias = gb[0];
    __syncthreads();

    // conv: 8 tap-groups (q = tid>>5, ~25 taps each), h = tid&31
    {
        int h = tid & 31, q = tid >> 5;            // q in [0,8)
        int k0 = (q * KFILT) / 8, k1 = ((q + 1) * KFILT) / 8;
        float acc[NCH];
        #pragma unroll
        for (int c = 0; c < NCH; ++c) acc[c] = 0.f;
        for (int k = k0; k < k1; ++k) {
            float s = cov_s[h + k];
            #pragma unroll
            for (int c = 0; c < NCH; ++c) acc[c] += s * cw[c * KFILT + k];
        }
        #pragma unroll
        for (int c = 0; c < NCH; ++c) pc[q][c][h] = acc[c];   // distinct slot per q
    }
    __syncthreads();
    for (int i = tid; i < NCH * HB; i += 256) {     // 320 entries
        int c = i >> 5, h = i & 31;
        float s = 0.f;
        #pragma unroll
        for (int q = 0; q < 8; ++q) s += pc[q][c][h];
        cfT[h * 12 + c] = s;
    }
    __syncthreads();

    // score: every thread computes its 2-a contribution for ALL 32 h.
    // pre reads: coalesced float2; cf reads: 3 broadcast ds_read_b128 per h.
    float ea[HB];
    const float2* pre2 = (const float2*)pre;
    int colf2 = (wv << 6) + lane;                   // float2 column = a/2
    #pragma unroll
    for (int hc = 0; hc < HB; hc += 8) {
        float2 Pr[8];
        #pragma unroll
        for (int j = 0; j < 8; ++j) Pr[j] = pre2[(h0 + hc + j) * 256 + colf2];
        #pragma unroll
        for (int j = 0; j < 8; ++j) {
            int h = hc + j;
            const float4* cp = (const float4*)&cfT[h * 12];
            float4 c0 = cp[0], c1 = cp[1], c2 = cp[2];
            float ch[NCH] = {c0.x, c0.y, c0.z, c0.w, c1.x, c1.y, c1.z, c1.w, c2.x, c2.y};
            float x0 = Pr[j].x + dz2.x;
            float x1 = Pr[j].y + dz2.y;
            #pragma unroll
            for (int c = 0; c < NCH; ++c) { x0 += ch[c] * W0[c]; x1 += ch[c] * W1[c]; }
            x0 = fminf(fmaxf(x0, -15.f), 15.f);
            x1 = fminf(fmaxf(x1, -15.f), 15.f);
            float z0 = __expf(2.f * x0), z1 = __expf(2.f * x1);
            float t0 = (z0 - 1.f) * __builtin_amdgcn_rcpf(z0 + 1.f);
            float t1 = (z1 - 1.f) * __builtin_amdgcn_rcpf(z1 + 1.f);
            ea[h] = t0 * gv2.x + t1 * gv2.y;
        }
    }

    // reduce-scatter butterfly over the wave: 63 shuffles total.
    // After 5 halving steps lane holds h = lane>>1 (summed over 32 lanes);
    // final off=1 exchange completes the 64-lane sum.
    #pragma unroll
    for (int k = 0; k < 16; ++k) {
        float up = __shfl_xor(ea[k + 16], 32, 64);
        float dn = __shfl_xor(ea[k], 32, 64);
        ea[k] = (lane & 32) ? (ea[k + 16] + up) : (ea[k] + dn);
    }
    #pragma unroll
    for (int k = 0; k < 8; ++k) {
        float up = __shfl_xor(ea[k + 8], 16, 64);
        float dn = __shfl_xor(ea[k], 16, 64);
        ea[k] = (lane & 16) ? (ea[k + 8] + up) : (ea[k] + dn);
    }
    #pragma unroll
    for (int k = 0; k < 4; ++k) {
        float up = __shfl_xor(ea[k + 4], 8, 64);
        float dn = __shfl_xor(ea[k], 8, 64);
        ea[k] = (lane & 8) ? (ea[k + 4] + up) : (ea[k] + dn);
    }
    #pragma unroll
    for (int k = 0; k < 2; ++k) {
        float up = __shfl_xor(ea[k + 2], 4, 64);
        float dn = __shfl_xor(ea[k], 4, 64);
        ea[k] = (lane & 4) ? (ea[k + 2] + up) : (ea[k] + dn);
    }
    {
        float up = __shfl_xor(ea[1], 2, 64);
        float dn = __shfl_xor(ea[0], 2, 64);
        ea[0] = (lane & 2) ? (ea[1] + up) : (ea[0] + dn);
    }
    ea[0] += __shfl_xor(ea[0], 1, 64);
    if ((lane & 1) == 0) ew[wv][lane >> 1] = ea[0];
    __syncthreads();

    // wave 0: combine 4 wave-partials, scale, block softmax partials
    if (wv == 0) {
        float v = -1e30f;
        if (lane < HB) {
            float e = ew[0][lane] + ew[1][lane] + ew[2][lane] + ew[3][lane];
            v = 2.f * (e + bias + mask_s[lane]);
            vbuf[h0 + lane] = v;
        }
        float m = v;
        #pragma unroll
        for (int off = 32; off > 0; off >>= 1) m = fmaxf(m, __shfl_xor(m, off, 64));
        float ev = (lane < HB) ? __expf(v - m) : 0.f;
        if (lane < HB) wt[lane] = ev;
        float s = ev;
        #pragma unroll
        for (int off = 32; off > 0; off >>= 1) s += __shfl_xor(s, off, 64);
        if (lane == 0) { pm[b] = m; ps[b] = s; }
    }
    __syncthreads();

    // unnormalized context partial: thread t owns enc cols {2t, 2t+1}
    const float2* enc2 = (const float2*)enc;
    float2 acc0 = {0.f, 0.f}, acc1 = {0.f, 0.f};
    #pragma unroll
    for (int h = 0; h < HB; h += 2) {
        float w0 = wt[h], w1 = wt[h + 1];
        float2 e0 = enc2[(h0 + h) * 256 + tid];
        float2 e1 = enc2[(h0 + h + 1) * 256 + tid];
        acc0.x += w0 * e0.x; acc0.y += w0 * e0.y;
        acc1.x += w1 * e1.x; acc1.y += w1 * e1.y;
    }
    float2 accv = {acc0.x + acc1.x, acc0.y + acc1.y};
    ((float2*)pcb)[b * 256 + tid] = accv;
}

// ---------------------------------------------------------------------------
// K3: finalize. 256 blocks x 256 thr. Redundant merge of 512 (m,s) partials
// (2 KB, L2-hot); block b writes w for 64 h; reduces pcb rows {2b,2b+1} into
// out_c with rescale, via atomics (256 adds/address).
__global__ __launch_bounds__(256) void k_final(const float* __restrict__ vbuf,
                                               const float* __restrict__ pm,
                                               const float* __restrict__ ps,
                                               const float* __restrict__ pcb,
                                               float* __restrict__ out_w,
                                               float* __restrict__ out_c) {
    __shared__ float redA[4], redB[4];
    int tid = threadIdx.x, b = blockIdx.x;
    int lane = tid & 63, wv = tid >> 6;

    float m0 = pm[tid], m1 = pm[tid + 256];
    float s0 = ps[tid], s1 = ps[tid + 256];
    float m = fmaxf(m0, m1);
    #pragma unroll
    for (int off = 32; off > 0; off >>= 1) m = fmaxf(m, __shfl_xor(m, off, 64));
    if (lane == 0) redA[wv] = m;
    __syncthreads();
    float M = fmaxf(fmaxf(redA[0], redA[1]), fmaxf(redA[2], redA[3]));
    float s = s0 * __expf(m0 - M) + s1 * __expf(m1 - M);
    #pragma unroll
    for (int off = 32; off > 0; off >>= 1) s += __shfl_xor(s, off, 64);
    if (lane == 0) redB[wv] = s;
    __syncthreads();
    float S = redB[0] + redB[1] + redB[2] + redB[3];
    float rinv = 1.f / S;

    // w output: 64 h per block
    if (tid < 64) {
        int h = b * 64 + tid;
        out_w[h] = __expf(vbuf[h] - M) * rinv;
    }

    // context reduction: rows 2b, 2b+1 of pcb
    int r0 = 2 * b, r1 = 2 * b + 1;
    float sc0 = __expf(pm[r0] - M) * rinv;
    float sc1 = __expf(pm[r1] - M) * rinv;
    float v0 = pcb[r0 * EPROJS + tid] * sc0 + pcb[r1 * EPROJS + tid] * sc1;
    float v1 = pcb[r0 * EPROJS + tid + 256] * sc0 + pcb[r1 * EPROJS + tid + 256] * sc1;
    atomicAdd(&out_c[tid], v0);
    atomicAdd(&out_c[tid + 256], v1);
}

// ---------------------------------------------------------------------------
extern "C" void kernel_launch(void* const* d_in, const int* in_sizes, int n_in,
                              void* d_out, int out_size, void* d_ws, size_t ws_size,
                              hipStream_t stream) {
    const float* dec_z      = (const float*)d_in[0];
    const float* att_prev   = (const float*)d_in[1];
    const float* pre        = (const float*)d_in[2];
    const float* enc_h      = (const float*)d_in[3];
    const float* mask       = (const float*)d_in[4];
    const float* loc_conv_w = (const float*)d_in[5];
    const float* mlp_att_w  = (const float*)d_in[6];
    const float* mlp_dec_w  = (const float*)d_in[7];
    const float* gvec_w     = (const float*)d_in[8];
    const float* gvec_b     = (const float*)d_in[9];

    float* out_c    = (float*)d_out;                  // [512]
    float* out_prev = out_c + EPROJS;                 // [128*16384]
    float* out_w    = out_prev + N_PREV * H_LEN;      // [16384]

    float* ws    = (float*)d_ws;
    float* cov16 = ws;                                // 16*16384
    float* dz    = cov16 + NCOVP * H_LEN;             // 512
    float* vb    = dz + ATT_DIM;                      // 16384
    float* pm    = vb + H_LEN;                        // 512
    float* ps    = pm + NB_SCORE;                     // 512
    float* pcb   = ps + NB_SCORE;                     // 512*512
    float* wattT = pcb + NB_SCORE * EPROJS;           // 10*512

    k_prep<<<385, 256, 0, stream>>>(att_prev, mlp_dec_w, dec_z, mlp_att_w,
                                    out_prev, cov16, dz, wattT, out_c);
    k_score<<<NB_SCORE, 256, 0, stream>>>(cov16, loc_conv_w, pre, mask, dz, wattT,
                                          gvec_w, gvec_b, enc_h, vb, pm, ps, pcb);
    k_final<<<NB_FIN, 256, 0, stream>>>(vb, pm, ps, pcb, out_w, out_c);
}